// Round 1
// baseline (356.238 us; speedup 1.0000x reference)
//
#include <hip/hip_runtime.h>
#include <math.h>

// GuidedAttentionLoss: loss = mean_b( sum_{f<F_b, l<L_b} (1 - exp(-(l/L - f/F)^2 * inv_denom)) * A[b,f,l] / F_b )
// A: [B=64, T_DEC=2048, T_ENC=512] fp32 (256 MB) -> pure streaming reduction, memory-bound.

#define BB     64
#define TDEC   2048
#define TENC   512
#define GSTEPS 20000
#define GAMMA  0.99995

// chunks of float4 along l: per-b chunks = TDEC * (TENC/4) = 2048*128 = 2^18
#define CHUNKS_PER_B (TDEC * (TENC / 4))
#define TOTAL_CHUNKS (BB * CHUNKS_PER_B)

// d_ws layout: [0] float inv_denom, [1] int active
__global__ void gal_prologue(const int* __restrict__ step_p,
                             float* __restrict__ ws,
                             float* __restrict__ out) {
    int step = step_p[0];
    double g = pow((double)GAMMA, (double)step);
    double inv_denom = 1.0 / (2.0 * g * g);
    ws[0] = (float)inv_denom;
    ((int*)ws)[1] = (GSTEPS < step) ? 0 : 1;
    out[0] = 0.0f;  // d_out is poisoned 0xAA before every replay
}

__global__ __launch_bounds__(256) void gal_main(
    const float* __restrict__ align,
    const int* __restrict__ in_len,    // L_b
    const int* __restrict__ tgt_len,   // F_b
    const float* __restrict__ ws,
    float* __restrict__ out) {

    const float inv_denom = ws[0];
    const int active = ((const int*)ws)[1];
    if (!active) return;  // out already zeroed by prologue

    // per-b params staged in LDS: F, L (int) and invF, invL, scale (float)
    __shared__ int   sF[BB];
    __shared__ int   sL[BB];
    __shared__ float sInvF[BB];
    __shared__ float sInvL[BB];
    __shared__ float sScale[BB];
    if (threadIdx.x < BB) {
        int b = threadIdx.x;
        int F = tgt_len[b];
        int L = in_len[b];
        sF[b] = F;
        sL[b] = L;
        float invF = 1.0f / (float)F;
        sInvF[b] = invF;
        sInvL[b] = 1.0f / (float)L;
        sScale[b] = invF * (1.0f / (float)BB);
    }
    __syncthreads();

    float acc = 0.0f;
    const int stride = gridDim.x * blockDim.x;
    for (int i = blockIdx.x * blockDim.x + threadIdx.x; i < TOTAL_CHUNKS; i += stride) {
        const int b   = i >> 18;                 // i / CHUNKS_PER_B
        const int rem = i & (CHUNKS_PER_B - 1);
        const int f   = rem >> 7;                // rem / (TENC/4)
        const int l0  = (rem & 127) << 2;        // first l of this float4

        const int F = sF[b];
        const int L = sL[b];
        if (f >= F || l0 >= L) continue;         // fully-masked chunk: skip the load

        const float4 a = ((const float4*)align)[i];
        const float fd = (float)f * sInvF[b];
        const float invL = sInvL[b];

        float s = 0.0f;
        #pragma unroll
        for (int j = 0; j < 4; ++j) {
            const int l = l0 + j;
            const float d = (float)l * invL - fd;
            const float w = 1.0f - __expf(-(d * d) * inv_denom);
            const float av = (&a.x)[j];
            if (l < L) s += w * av;              // partial-chunk mask on l
        }
        acc += s * sScale[b];
    }

    // wave(64) shuffle reduce -> LDS -> block -> one atomic per block
    #pragma unroll
    for (int off = 32; off > 0; off >>= 1) acc += __shfl_down(acc, off, 64);
    __shared__ float swave[4];   // 256 threads / 64
    const int lane = threadIdx.x & 63;
    const int wid  = threadIdx.x >> 6;
    if (lane == 0) swave[wid] = acc;
    __syncthreads();
    if (threadIdx.x == 0) {
        float sblk = swave[0] + swave[1] + swave[2] + swave[3];
        atomicAdd(out, sblk);
    }
}

extern "C" void kernel_launch(void* const* d_in, const int* in_sizes, int n_in,
                              void* d_out, int out_size, void* d_ws, size_t ws_size,
                              hipStream_t stream) {
    const float* align   = (const float*)d_in[0];
    const int*   in_len  = (const int*)d_in[1];
    const int*   tgt_len = (const int*)d_in[2];
    const int*   step_p  = (const int*)d_in[3];
    float* out = (float*)d_out;
    float* ws  = (float*)d_ws;

    gal_prologue<<<1, 1, 0, stream>>>(step_p, ws, out);

    const int block = 256;
    const int grid  = 4096;   // 1M threads, 16 float4-chunks each over 16M chunks
    gal_main<<<grid, block, 0, stream>>>(align, in_len, tgt_len, ws, out);
}

// Round 4
// 347.608 us; speedup vs baseline: 1.0248x; 1.0248x over previous
//
#include <hip/hip_runtime.h>

// GuidedAttentionLoss: loss = mean_b( sum_{f<F_b, l<L_b} (1 - exp(-(l/L - f/F)^2 * inv_denom)) * A[b,f,l] / F_b )
// A: [B=64, T_DEC=2048, T_ENC=512] fp32 (256 MB) -> streaming reduction, memory-bound.
//
// Structure: 1 block per (b, 64-row slab) => F,L are block-uniform. Row skip
// (f >= F) is a uniform loop bound (saves ~25% traffic, no divergence).
// Loads are unconditional float4 (array fully allocated; l>=L masked by a
// precomputed 0/1 float) => branch-free body, unroll-4 keeps 4 loads in
// flight per thread => BW-bound, not latency-bound.

#define BB     64
#define TDEC   2048
#define TENC   512
#define GSTEPS 20000
#define GAMMA  0.99995
#define SLABS  32
#define SLAB_ROWS (TDEC / SLABS)   // 64
#define LOG2E  1.4426950408889634f

// d_ws layout: [0] float inv_denom, [1] int active
__global__ void gal_prologue(const int* __restrict__ step_p,
                             float* __restrict__ ws,
                             float* __restrict__ out) {
    int step = step_p[0];
    // g = GAMMA^step by exponentiation-by-squaring (no libcalls on device)
    double g = 1.0, base = GAMMA;
    unsigned e = (step > 0) ? (unsigned)step : 0u;
    while (e) {
        if (e & 1u) g *= base;
        base *= base;
        e >>= 1;
    }
    ws[0] = (float)(1.0 / (2.0 * g * g));
    ((int*)ws)[1] = (GSTEPS < step) ? 0 : 1;
    out[0] = 0.0f;  // d_out is poisoned 0xAA before every replay
}

__global__ __launch_bounds__(256) void gal_main(
    const float* __restrict__ align,
    const int* __restrict__ in_len,    // L_b
    const int* __restrict__ tgt_len,   // F_b
    const float* __restrict__ ws,
    float* __restrict__ out) {

    const int b          = blockIdx.x >> 5;       // / SLABS
    const int slab       = blockIdx.x & (SLABS - 1);
    const int slab_start = slab * SLAB_ROWS;

    const float inv_denom = ws[0];
    const int   active    = ((const int*)ws)[1];

    const int F = tgt_len[b];
    const int L = in_len[b];

    float acc = 0.0f;

    const int rows_end = min(slab_start + SLAB_ROWS, F);
    const int nrows    = rows_end - slab_start;

    if (active && nrows > 0) {
        const int tid = threadIdx.x;
        const int col = tid & 127;       // float4 column within the 512-wide row
        const int r   = tid >> 7;        // 0 or 1: which of the 2 rows per iter
        const int l0  = col << 2;

        const float invF = 1.0f / (float)F;
        const float invL = 1.0f / (float)L;
        const float c    = -inv_denom * LOG2E;   // exp(x) = exp2(x*log2e), sign folded

        // per-lane loop invariants
        float lv[4], cm[4];
        #pragma unroll
        for (int j = 0; j < 4; ++j) {
            const int l = l0 + j;
            lv[j] = (float)l * invL;
            cm[j] = (l < L) ? 1.0f : 0.0f;       // l-mask folded into the data
        }

        const float4* p = (const float4*)(align + ((size_t)b * TDEC + slab_start + r) * TENC) + col;
        const int nev = nrows & ~1;              // rows both halves can do

        #pragma unroll 4
        for (int k = 0; k < nev; k += 2) {
            const float4 a  = *p;                // unconditional, pipelines
            const float  fd = (float)(slab_start + k + r) * invF;
            #pragma unroll
            for (int j = 0; j < 4; ++j) {
                const float d   = lv[j] - fd;
                const float e   = __builtin_amdgcn_exp2f((d * c) * d);  // exp(-d^2*inv_denom)
                const float am  = (&a.x)[j] * cm[j];
                acc += am;                                 // (1-e)*am = am - e*am
                acc  = fmaf(-e, am, acc);
            }
            p += 2 * (TENC / 4);                 // advance 2 rows
        }

        // odd tail row: only the r==0 half-block handles it; p already points there
        if ((nrows & 1) && r == 0) {
            const float4 a  = *p;
            const float  fd = (float)(rows_end - 1) * invF;
            #pragma unroll
            for (int j = 0; j < 4; ++j) {
                const float d  = lv[j] - fd;
                const float e  = __builtin_amdgcn_exp2f((d * c) * d);
                const float am = (&a.x)[j] * cm[j];
                acc += am;
                acc  = fmaf(-e, am, acc);
            }
        }

        acc *= invF * (1.0f / (float)BB);        // /F_b and /B (mean)
    }

    // wave(64) shuffle reduce -> LDS -> block -> one atomic per block
    #pragma unroll
    for (int off = 32; off > 0; off >>= 1) acc += __shfl_down(acc, off, 64);
    __shared__ float swave[4];   // 256 threads / 64
    const int lane = threadIdx.x & 63;
    const int wid  = threadIdx.x >> 6;
    if (lane == 0) swave[wid] = acc;
    __syncthreads();
    if (threadIdx.x == 0) {
        atomicAdd(out, swave[0] + swave[1] + swave[2] + swave[3]);
    }
}

extern "C" void kernel_launch(void* const* d_in, const int* in_sizes, int n_in,
                              void* d_out, int out_size, void* d_ws, size_t ws_size,
                              hipStream_t stream) {
    const float* align   = (const float*)d_in[0];
    const int*   in_len  = (const int*)d_in[1];
    const int*   tgt_len = (const int*)d_in[2];
    const int*   step_p  = (const int*)d_in[3];
    float* out = (float*)d_out;
    float* ws  = (float*)d_ws;

    gal_prologue<<<1, 1, 0, stream>>>(step_p, ws, out);

    gal_main<<<BB * SLABS, 256, 0, stream>>>(align, in_len, tgt_len, ws, out);
}

// Round 5
// 334.152 us; speedup vs baseline: 1.0661x; 1.0403x over previous
//
#include <hip/hip_runtime.h>

// GuidedAttentionLoss: loss = mean_b( sum_{f<F_b, l<L_b} (1 - exp(-(l/L - f/F)^2 * inv_denom)) * A[b,f,l] / F_b )
// A: [B=64, T_DEC=2048, T_ENC=512] fp32 (256 MB) -> streaming reduction, memory-bound.
//
// Structure: 1 block per (b, 64-row slab); F,L block-uniform.
//  - Row skip (f >= F): uniform loop bound, saves 25% traffic, no divergence.
//  - Column skip (l >= L): per-lane loop-INVARIANT predicate wraps the whole
//    k-loop -> exec-masked loads, cache-line-granular fetch skip (~25% more).
//  - No prologue dependency: every block computes inv_denom locally (cheap
//    wave-uniform double mults); per-block partials to ws, tiny epilogue sums.

#define BB     64
#define TDEC   2048
#define TENC   512
#define GSTEPS 20000
#define GAMMA  0.99995
#define SLABS  32
#define SLAB_ROWS (TDEC / SLABS)   // 64
#define NBLK   (BB * SLABS)        // 2048
#define LOG2E  1.4426950408889634f

__device__ inline double gal_pow_gamma(int step) {
    // GAMMA^step by exponentiation-by-squaring (no libcalls)
    double g = 1.0, base = GAMMA;
    unsigned e = (step > 0) ? (unsigned)step : 0u;
    while (e) {
        if (e & 1u) g *= base;
        base *= base;
        e >>= 1;
    }
    return g;
}

__global__ __launch_bounds__(256) void gal_main(
    const float* __restrict__ align,
    const int* __restrict__ in_len,    // L_b
    const int* __restrict__ tgt_len,   // F_b
    const int* __restrict__ step_p,
    float* __restrict__ partials) {

    const int b          = blockIdx.x >> 5;       // / SLABS
    const int slab       = blockIdx.x & (SLABS - 1);
    const int slab_start = slab * SLAB_ROWS;

    const int step   = step_p[0];
    const int active = (GSTEPS < step) ? 0 : 1;

    const int F = tgt_len[b];
    const int L = in_len[b];

    float acc = 0.0f;

    const int rows_end = min(slab_start + SLAB_ROWS, F);
    const int nrows    = rows_end - slab_start;

    const int tid = threadIdx.x;
    const int col = tid & 127;       // float4 column within the 512-wide row
    const int r   = tid >> 7;        // 0 or 1: which of the 2 rows per iter
    const int l0  = col << 2;

    if (active && nrows > 0 && l0 < L) {   // lane-invariant column skip
        const double g = gal_pow_gamma(step);
        const float inv_denom = (float)(1.0 / (2.0 * g * g));

        const float invF = 1.0f / (float)F;
        const float invL = 1.0f / (float)L;
        const float c    = -inv_denom * LOG2E;   // exp(x) = exp2(x*log2e), sign folded

        // per-lane loop invariants
        float lv[4], cm[4];
        #pragma unroll
        for (int j = 0; j < 4; ++j) {
            const int l = l0 + j;
            lv[j] = (float)l * invL;
            cm[j] = (l < L) ? 1.0f : 0.0f;       // partial-float4 l-mask
        }

        const float4* p = (const float4*)(align + ((size_t)b * TDEC + slab_start + r) * TENC) + col;
        const int nev = nrows & ~1;              // rows both halves can do

        #pragma unroll 4
        for (int k = 0; k < nev; k += 2) {
            const float4 a  = *p;                // pipelines; exec-masked lanes fetch nothing
            const float  fd = (float)(slab_start + k + r) * invF;
            #pragma unroll
            for (int j = 0; j < 4; ++j) {
                const float d  = lv[j] - fd;
                const float e  = __builtin_amdgcn_exp2f((d * c) * d);  // exp(-d^2*inv_denom)
                const float am = (&a.x)[j] * cm[j];
                acc += am;                                 // (1-e)*am = am - e*am
                acc  = fmaf(-e, am, acc);
            }
            p += 2 * (TENC / 4);                 // advance 2 rows
        }

        // odd tail row: only the r==0 half handles it; p already points there
        if ((nrows & 1) && r == 0) {
            const float4 a  = *p;
            const float  fd = (float)(rows_end - 1) * invF;
            #pragma unroll
            for (int j = 0; j < 4; ++j) {
                const float d  = lv[j] - fd;
                const float e  = __builtin_amdgcn_exp2f((d * c) * d);
                const float am = (&a.x)[j] * cm[j];
                acc += am;
                acc  = fmaf(-e, am, acc);
            }
        }

        acc *= invF * (1.0f / (float)BB);        // /F_b and /B (mean)
    }

    // wave(64) shuffle reduce -> LDS -> block partial (ws is poisoned: always write)
    #pragma unroll
    for (int off = 32; off > 0; off >>= 1) acc += __shfl_down(acc, off, 64);
    __shared__ float swave[4];   // 256 threads / 64
    const int lane = threadIdx.x & 63;
    const int wid  = threadIdx.x >> 6;
    if (lane == 0) swave[wid] = acc;
    __syncthreads();
    if (threadIdx.x == 0) {
        partials[blockIdx.x] = swave[0] + swave[1] + swave[2] + swave[3];
    }
}

__global__ __launch_bounds__(256) void gal_epilogue(
    const float* __restrict__ partials,
    const int* __restrict__ step_p,
    float* __restrict__ out) {

    const int step   = step_p[0];
    const int active = (GSTEPS < step) ? 0 : 1;

    float acc = 0.0f;
    if (active) {
        #pragma unroll
        for (int k = 0; k < NBLK / 256; ++k)     // 8 each
            acc += partials[k * 256 + threadIdx.x];
    }
    #pragma unroll
    for (int off = 32; off > 0; off >>= 1) acc += __shfl_down(acc, off, 64);
    __shared__ float swave[4];
    const int lane = threadIdx.x & 63;
    const int wid  = threadIdx.x >> 6;
    if (lane == 0) swave[wid] = acc;
    __syncthreads();
    if (threadIdx.x == 0) {
        out[0] = swave[0] + swave[1] + swave[2] + swave[3];  // 0 if inactive
    }
}

extern "C" void kernel_launch(void* const* d_in, const int* in_sizes, int n_in,
                              void* d_out, int out_size, void* d_ws, size_t ws_size,
                              hipStream_t stream) {
    const float* align   = (const float*)d_in[0];
    const int*   in_len  = (const int*)d_in[1];
    const int*   tgt_len = (const int*)d_in[2];
    const int*   step_p  = (const int*)d_in[3];
    float* out      = (float*)d_out;
    float* partials = (float*)d_ws;    // NBLK floats

    gal_main<<<NBLK, 256, 0, stream>>>(align, in_len, tgt_len, step_p, partials);
    gal_epilogue<<<1, 256, 0, stream>>>(partials, step_p, out);
}